// Round 8
// baseline (283.517 us; speedup 1.0000x reference)
//
#include <hip/hip_runtime.h>
#include <math.h>

// Sizes: b=4, t=12 (BT=48), n=512, c=64, heads=8, hd=8, FF hidden=256, depth=2

typedef __fp16 half_t;
typedef __attribute__((ext_vector_type(2))) __fp16 half2v;
typedef __attribute__((ext_vector_type(4))) __fp16 half4v;
typedef __attribute__((ext_vector_type(4))) float f32x4;

union PU  { half2v h2[2]; half4v h4; };
union F4H { float4 f; half4v h[2]; };
union F2H { float2 f2; half4v h4; };

#define ATS 72
#define BTS 68
#define VTS 516

// ---------------- merged prologue: init-transpose (h+hh) | adjt | weight-prep | adj^2 ----------------
__global__ __launch_bounds__(256) void k_pre(const float* __restrict__ x,
                                             const float* __restrict__ pos,
                                             const float* __restrict__ adj,
                                             const float* __restrict__ qkv_w,
                                             const float* __restrict__ proj_w,
                                             const float* __restrict__ ff_w1,
                                             const float* __restrict__ ff_w2,
                                             const float* __restrict__ gcn_w,
                                             float* __restrict__ h,
                                             half_t* __restrict__ hh,
                                             half_t* __restrict__ adjTh,
                                             half_t* __restrict__ wh,
                                             half_t* __restrict__ adjT2h) {
    __shared__ __align__(16) char smem[17920];
    float* t = (float*)smem;                          // 64*65 floats = 16640 B
    int tid = threadIdx.x;
    int bidx = blockIdx.x;
    if (bidx < 384) {
        int b = bidx / 96, vt0 = (bidx % 96) * 64;
#pragma unroll
        for (int i = 0; i < 4; ++i) {
            int g = tid + i * 256;
            int r = g >> 4, q = g & 15;
            *(float4*)&t[r * 65 + 4 * q] =
                *(const float4*)(x + ((size_t)(b * 64 + r)) * 6144 + vt0 + 4 * q);
        }
        __syncthreads();
#pragma unroll
        for (int i = 0; i < 4; ++i) {
            int g = tid + i * 256;
            int r = g >> 4, q = g & 15;
            int vt = vt0 + r;
            int v = vt / 12, tt = vt - v * 12;
            float4 pv = *(const float4*)(pos + v * 64 + 4 * q);
            float4 o;
            o.x = t[(4 * q + 0) * 65 + r] + pv.x;
            o.y = t[(4 * q + 1) * 65 + r] + pv.y;
            o.z = t[(4 * q + 2) * 65 + r] + pv.z;
            o.w = t[(4 * q + 3) * 65 + r] + pv.w;
            size_t idx = ((size_t)((b * 12 + tt) * 512 + v)) * 64 + 4 * q;
            *(float4*)(h + idx) = o;
            PU u;
            u.h2[0] = __builtin_amdgcn_cvt_pkrtz(o.x, o.y);
            u.h2[1] = __builtin_amdgcn_cvt_pkrtz(o.z, o.w);
            *(half4v*)(hh + idx) = u.h4;
        }
    } else if (bidx < 448) {
        int fb = bidx - 384;
        int v0 = (fb & 7) * 64, w0 = (fb >> 3) * 64;
#pragma unroll
        for (int i = 0; i < 4; ++i) {
            int g = tid + i * 256;
            int r = g >> 4, q = g & 15;
            float4 a = *(const float4*)(adj + (size_t)(v0 + r) * 512 + w0 + 4 * q);
            t[(4 * q + 0) * 65 + r] = a.x;
            t[(4 * q + 1) * 65 + r] = a.y;
            t[(4 * q + 2) * 65 + r] = a.z;
            t[(4 * q + 3) * 65 + r] = a.w;
        }
        __syncthreads();
#pragma unroll
        for (int i = 0; i < 4; ++i) {
            int g = tid + i * 256;
            int rw = g >> 4, q = g & 15;
            const float* src = &t[rw * 65 + 4 * q];
            PU u;
            u.h2[0] = __builtin_amdgcn_cvt_pkrtz(src[0], src[1]);
            u.h2[1] = __builtin_amdgcn_cvt_pkrtz(src[2], src[3]);
            *(half4v*)(adjTh + (size_t)(w0 + rw) * 512 + v0 + 4 * q) = u.h4;
        }
    } else if (bidx < 568) {
        // vectorized weight fp32->fp16: 120 blocks x 256 thr x 4 el = 122880
        int i = ((bidx - 448) * 256 + tid) * 4;
        float4 v;
        if (i < 24576) v = *(const float4*)(qkv_w + i);
        else if (i < 32768) v = *(const float4*)(proj_w + (i - 24576));
        else if (i < 65536) v = *(const float4*)(ff_w1 + (i - 32768));
        else if (i < 98304) v = *(const float4*)(ff_w2 + (i - 65536));
        else v = *(const float4*)(gcn_w + (i - 98304));
        PU u;
        u.h2[0] = __builtin_amdgcn_cvt_pkrtz(v.x, v.y);
        u.h2[1] = __builtin_amdgcn_cvt_pkrtz(v.z, v.w);
        *(half4v*)(wh + i) = u.h4;
    } else {
        half_t* a_t = (half_t*)smem;
        half_t* b_t = (half_t*)smem + 64 * ATS;
        int fb = bidx - 568;
        int w0 = (fb & 7) * 64, v0 = (fb >> 3) * 64;
        int wave = tid >> 6, lane = tid & 63;
        int lm = lane & 15, lg = lane >> 4;
        const f32x4 zc = {0.f, 0.f, 0.f, 0.f};
        f32x4 acc[4] = {zc, zc, zc, zc};
        for (int kc = 0; kc < 8; ++kc) {
#pragma unroll
            for (int i = 0; i < 4; ++i) {
                int g = tid + i * 256;
                int uu = g >> 4, q = g & 15;
                float4 a = *(const float4*)(adj + (size_t)(kc * 64 + uu) * 512 + w0 + 4 * q);
                a_t[(4 * q + 0) * ATS + uu] = (half_t)a.x;
                a_t[(4 * q + 1) * ATS + uu] = (half_t)a.y;
                a_t[(4 * q + 2) * ATS + uu] = (half_t)a.z;
                a_t[(4 * q + 3) * ATS + uu] = (half_t)a.w;
            }
#pragma unroll
            for (int i = 0; i < 4; ++i) {
                int g = tid + i * 256;
                int c = g >> 4, q = g & 15;
                float4 a = *(const float4*)(adj + (size_t)(v0 + c) * 512 + kc * 64 + 4 * q);
                PU u;
                u.h2[0] = __builtin_amdgcn_cvt_pkrtz(a.x, a.y);
                u.h2[1] = __builtin_amdgcn_cvt_pkrtz(a.z, a.w);
                *(half4v*)&b_t[c * BTS + 4 * q] = u.h4;
            }
            __syncthreads();
#pragma unroll
            for (int k16 = 0; k16 < 4; ++k16) {
                half4v af = *(const half4v*)&a_t[(wave * 16 + lm) * ATS + k16 * 16 + lg * 4];
#pragma unroll
                for (int nt = 0; nt < 4; ++nt) {
                    half4v bf = *(const half4v*)&b_t[(nt * 16 + lm) * BTS + k16 * 16 + lg * 4];
                    acc[nt] = __builtin_amdgcn_mfma_f32_16x16x16f16(af, bf, acc[nt], 0, 0, 0);
                }
            }
            __syncthreads();
        }
#pragma unroll
        for (int nt = 0; nt < 4; ++nt)
#pragma unroll
            for (int r = 0; r < 4; ++r)
                adjT2h[(size_t)(w0 + wave * 16 + lg * 4 + r) * 512 + v0 + nt * 16 + lm] =
                    (half_t)acc[nt][r];
    }
}

// ---------------- merged: qkv (blocks 0..383) | diff z-merged (blocks 384..767) ----------------
__global__ __launch_bounds__(256) void k_qd(const half_t* __restrict__ hh,
                                            const half_t* __restrict__ Wh,
                                            half_t* __restrict__ qh,
                                            half_t* __restrict__ kh,
                                            half_t* __restrict__ vh,
                                            const half_t* __restrict__ adjTh,
                                            const half_t* __restrict__ adjT2h,
                                            half_t* __restrict__ x1h,
                                            half_t* __restrict__ x2h) {
    __shared__ __align__(16) half_t sbuf[2 * 64 * ATS + 64 * BTS];   // 27136 B
    int tid = threadIdx.x;
    int bidx = blockIdx.x;
    int wave = tid >> 6, lane = tid & 63;
    int lm = lane & 15, lg = lane >> 4;
    const f32x4 zc = {0.f, 0.f, 0.f, 0.f};

    if (bidx < 384) {
        int wid = bidx * 4 + wave;
        int row = wid * 16 + lm;
        half4v xf[4];
#pragma unroll
        for (int kc = 0; kc < 4; ++kc) {
            F2H u;
            u.f2 = *(const float2*)(hh + (size_t)row * 64 + kc * 16 + lg * 4);
            xf[kc] = u.h4;
        }
        const float SC = 0.35355339059327373f * 1.4426950408889634f;
        int bt = row >> 9, v = row & 511;
        half4v wf[4];
#pragma unroll
        for (int kc = 0; kc < 4; ++kc)
            wf[kc] = *(const half4v*)(Wh + (size_t)lm * 64 + kc * 16 + lg * 4);
#pragma unroll
        for (int nt = 0; nt < 12; ++nt) {
            half4v cw[4];
#pragma unroll
            for (int kc = 0; kc < 4; ++kc) cw[kc] = wf[kc];
            if (nt < 11) {
#pragma unroll
                for (int kc = 0; kc < 4; ++kc)
                    wf[kc] = *(const half4v*)(Wh + (size_t)((nt + 1) * 16 + lm) * 64 + kc * 16 + lg * 4);
            }
            f32x4 acc = zc;
#pragma unroll
            for (int kc = 0; kc < 4; ++kc)
                acc = __builtin_amdgcn_mfma_f32_16x16x16f16(cw[kc], xf[kc], acc, 0, 0, 0);
            int s = nt >> 2;
            if (s == 0) { acc[0] *= SC; acc[1] *= SC; acc[2] *= SC; acc[3] *= SC; }
            int head = ((nt & 3) << 1) + (lg >> 1);
            int d0 = (lg & 1) * 4;
            PU o2;
            o2.h2[0] = __builtin_amdgcn_cvt_pkrtz(acc[0], acc[1]);
            o2.h2[1] = __builtin_amdgcn_cvt_pkrtz(acc[2], acc[3]);
            half_t* dst = (s == 0) ? qh : ((s == 1) ? kh : vh);
            *(half4v*)(dst + ((size_t)(bt * 8 + head) * 512 + v) * 8 + d0) = o2.h4;
        }
    } else {
        half_t* a_t  = sbuf;
        half_t* a2_t = sbuf + 64 * ATS;
        half_t* b_t  = sbuf + 2 * 64 * ATS;
        int fb = bidx - 384;                    // 0..383
        int w0 = (fb & 7) * 64;
        int bt = fb >> 3;
        f32x4 acc0[4] = {zc, zc, zc, zc};
        f32x4 acc1[4] = {zc, zc, zc, zc};
        for (int kc = 0; kc < 8; ++kc) {
#pragma unroll
            for (int i = 0; i < 4; ++i) {       // 1024 items: 512 adjTh + 512 adjT2h
                int g = tid + i * 256;
                if (g < 512) {
                    int r = g >> 3, s = g & 7;
                    *(float4*)&a_t[r * ATS + s * 8] =
                        *(const float4*)(adjTh + (size_t)(w0 + r) * 512 + kc * 64 + s * 8);
                } else {
                    int g2 = g - 512;
                    int r = g2 >> 3, s = g2 & 7;
                    *(float4*)&a2_t[r * ATS + s * 8] =
                        *(const float4*)(adjT2h + (size_t)(w0 + r) * 512 + kc * 64 + s * 8);
                }
            }
#pragma unroll
            for (int i = 0; i < 2; ++i) {       // 512 items: transpose-stage hh tile
                int g = tid + i * 256;
                int vr = g >> 3, s = g & 7;
                F4H u;
                u.f = *(const float4*)(hh + ((size_t)(bt * 512 + kc * 64 + vr)) * 64 + s * 8);
#pragma unroll
                for (int e = 0; e < 8; ++e)
                    b_t[(s * 8 + e) * BTS + vr] = u.h[e >> 2][e & 3];
            }
            __syncthreads();
#pragma unroll
            for (int k16 = 0; k16 < 4; ++k16) {
                half4v af0 = *(const half4v*)&a_t[(wave * 16 + lm) * ATS + k16 * 16 + lg * 4];
                half4v af1 = *(const half4v*)&a2_t[(wave * 16 + lm) * ATS + k16 * 16 + lg * 4];
#pragma unroll
                for (int nt = 0; nt < 4; ++nt) {
                    half4v bf = *(const half4v*)&b_t[(nt * 16 + lm) * BTS + k16 * 16 + lg * 4];
                    acc0[nt] = __builtin_amdgcn_mfma_f32_16x16x16f16(af0, bf, acc0[nt], 0, 0, 0);
                    acc1[nt] = __builtin_amdgcn_mfma_f32_16x16x16f16(af1, bf, acc1[nt], 0, 0, 0);
                }
            }
            __syncthreads();
        }
        // vectorized epilogue: bounce acc tiles through LDS (stride 72 halves = 144 B, 16B-aligned)
        half_t* x1s = sbuf;
        half_t* x2s = sbuf + 64 * 72;
#pragma unroll
        for (int nt = 0; nt < 4; ++nt)
#pragma unroll
            for (int r = 0; r < 4; ++r) {
                int vrow = wave * 16 + lg * 4 + r;
                x1s[vrow * 72 + nt * 16 + lm] = (half_t)acc0[nt][r];
                x2s[vrow * 72 + nt * 16 + lm] = (half_t)acc1[nt][r];
            }
        __syncthreads();
#pragma unroll
        for (int i = 0; i < 2; ++i) {
            int g = tid + i * 256;
            int r = g >> 3, s = g & 7;
            size_t o = (size_t)(w0 + r) * 3072 + bt * 64 + s * 8;
            *(float4*)(x1h + o) = *(const float4*)&x1s[r * 72 + s * 8];
            *(float4*)(x2h + o) = *(const float4*)&x2s[r * 72 + s * 8];
        }
    }
}

// ---------------- merged: attn slim-LDS (blocks 0..767) | gcn all-512-thread (blocks 768..1151) ----------------
__global__ __launch_bounds__(512) void k_ag(const half_t* __restrict__ qh,
                                            const half_t* __restrict__ kh,
                                            const half_t* __restrict__ vh,
                                            half_t* __restrict__ obh,
                                            const half_t* __restrict__ hh,
                                            const half_t* __restrict__ x1h,
                                            const half_t* __restrict__ x2h,
                                            const half_t* __restrict__ Wh,
                                            const float* __restrict__ bias,
                                            float* __restrict__ gout) {
    // attn: kl 512x8 (8192 B) + vt 8x516 (8256 B) + ql 256x8 (4096 B) = 20544 B -> 4 blocks/CU
    __shared__ __align__(16) half_t sbuf[10272];
    int tid = threadIdx.x;
    int bidx = blockIdx.x;
    const half4v zero4 = {(__fp16)0.f, (__fp16)0.f, (__fp16)0.f, (__fp16)0.f};
    const f32x4 zc = {0.f, 0.f, 0.f, 0.f};

    if (bidx < 768) {
        half_t* kl = sbuf;                       // 512 keys x 8 d
        half_t* vt = sbuf + 4096;                // 8 d x 516 keys
        half_t* ql = sbuf + 4096 + 8 * VTS;      // 256 q x 8 d
        int bh = bidx >> 1;
        int half_ = bidx & 1;
        const half_t* kbase = kh + (size_t)bh * 4096;
        const half_t* vbase = vh + (size_t)bh * 4096;
        const half_t* qbase = qh + (size_t)bh * 4096 + half_ * 2048;

        if (tid < 256) {
            *(float4*)&kl[tid * 16]     = *(const float4*)(kbase + tid * 16);
            *(float4*)&kl[tid * 16 + 8] = *(const float4*)(kbase + tid * 16 + 8);
            *(float4*)&ql[tid * 8]      = *(const float4*)(qbase + tid * 8);
            {
                int k0 = tid * 2;
                F4H a, b;
                a.f = *(const float4*)(vbase + k0 * 8);
                b.f = *(const float4*)(vbase + k0 * 8 + 8);
#pragma unroll
                for (int d = 0; d < 8; ++d) {
                    half2v p = {a.h[d >> 2][d & 3], b.h[d >> 2][d & 3]};
                    *(half2v*)&vt[d * VTS + k0] = p;
                }
            }
        }
        __syncthreads();

        int wave = tid >> 6, lane = tid & 63;
        int lm = lane & 15, lg = lane >> 4;
        int bt = bh >> 3, head = bh & 7;

#pragma unroll 1
        for (int st = 0; st < 2; ++st) {
            int qrow0 = wave * 32 + st * 16;
            half4v qt = *(const half4v*)&ql[(qrow0 + lm) * 8 + (lg & 1) * 4];
            half4v qf = (lg < 2) ? qt : zero4;
            f32x4 acc = zc;
            float l0 = 0.f, l1 = 0.f, l2 = 0.f, l3 = 0.f;
#pragma unroll 4
            for (int kt = 0; kt < 32; ++kt) {
                int key0 = kt * 16;
                half4v kt_ = *(const half4v*)&kl[(key0 + lm) * 8 + (lg & 1) * 4];
                half4v ka = (lg < 2) ? kt_ : zero4;
                f32x4 c1 = __builtin_amdgcn_mfma_f32_16x16x16f16(ka, qf, zc, 0, 0, 0);
                float p0 = exp2f(fminf(c1[0], 12.f));
                float p1 = exp2f(fminf(c1[1], 12.f));
                float p2 = exp2f(fminf(c1[2], 12.f));
                float p3 = exp2f(fminf(c1[3], 12.f));
                l0 += p0; l1 += p1; l2 += p2; l3 += p3;
                PU pu;
                pu.h2[0] = __builtin_amdgcn_cvt_pkrtz(p0, p1);
                pu.h2[1] = __builtin_amdgcn_cvt_pkrtz(p2, p3);
                half4v vv = *(const half4v*)&vt[(lm & 7) * VTS + key0 + lg * 4];
                half4v va = (lm < 8) ? vv : zero4;
                acc = __builtin_amdgcn_mfma_f32_16x16x16f16(va, pu.h4, acc, 0, 0, 0);
            }
            float lsum = (l0 + l1) + (l2 + l3);
            lsum += __shfl_xor(lsum, 16);
            lsum += __shfl_xor(lsum, 32);
            if (lg < 2) {
                float inv = 1.f / lsum;
                int rowg = half_ * 256 + qrow0 + lm;
                PU o2;
                o2.h2[0] = __builtin_amdgcn_cvt_pkrtz(acc[0] * inv, acc[1] * inv);
                o2.h2[1] = __builtin_amdgcn_cvt_pkrtz(acc[2] * inv, acc[3] * inv);
                *(half4v*)(obh + ((size_t)(bt * 512 + rowg)) * 64 + head * 8 + lg * 4) = o2.h4;
            }
        }
    } else {
        // GCN: 64 output rows x 64 cols per block, all 8 waves active. (needs 8960 halves <= 10272)
        half_t* a_t = sbuf;
        half_t* b_t = sbuf + 64 * ATS;
        int row0 = (bidx - 768) * 64;
        int wave = tid >> 6, lane = tid & 63;
        int lm = lane & 15, lg = lane >> 4;
        int wr = wave & 3;
        int wn = wave >> 2;
        f32x4 acc[2] = {zc, zc};

        for (int ch = 0; ch < 3; ++ch) {
            {
                int g = tid;                       // 512 items: stage A rows
                int r = g >> 3, s = g & 7;
                if (ch == 0) {
                    int rowg = row0 + r;
                    int v = rowg / 48, bt = rowg - v * 48;
                    *(float4*)&a_t[r * ATS + s * 8] =
                        *(const float4*)(hh + ((size_t)(bt * 512 + v)) * 64 + s * 8);
                } else {
                    const half_t* X = (ch == 1) ? x1h : x2h;
                    *(float4*)&a_t[r * ATS + s * 8] =
                        *(const float4*)(X + (size_t)(row0 + r) * 64 + s * 8);
                }
            }
#pragma unroll
            for (int i = 0; i < 2; ++i) {          // 1024 items: stage W tile
                int g = tid + i * 512;
                int r = g >> 4, q = g & 15;
                *(half4v*)&b_t[r * BTS + 4 * q] =
                    *(const half4v*)(Wh + (size_t)r * 192 + ch * 64 + 4 * q);
            }
            __syncthreads();
#pragma unroll
            for (int k16 = 0; k16 < 4; ++k16) {
                half4v af = *(const half4v*)&a_t[(wr * 16 + lm) * ATS + k16 * 16 + lg * 4];
#pragma unroll
                for (int j = 0; j < 2; ++j) {
                    int nt = wn * 2 + j;
                    half4v bf = *(const half4v*)&b_t[(nt * 16 + lm) * BTS + k16 * 16 + lg * 4];
                    acc[j] = __builtin_amdgcn_mfma_f32_16x16x16f16(bf, af, acc[j], 0, 0, 0);
                }
            }
            __syncthreads();
        }
        {
            int row = row0 + wr * 16 + lm;
            int v = row / 48, bt = row - v * 48;
            float* gp = gout + ((size_t)(bt * 512 + v)) * 64;
#pragma unroll
            for (int j = 0; j < 2; ++j) {
                int nt = wn * 2 + j;
                float4 bb = *(const float4*)(bias + nt * 16 + lg * 4);
                *(float4*)(gp + nt * 16 + lg * 4) =
                    make_float4(acc[j][0] + bb.x, acc[j][1] + bb.y,
                                acc[j][2] + bb.z, acc[j][3] + bb.w);
            }
        }
    }
}

// ---------------- fused proj + LN + FF + gout add; writes h/hh (l=0) or out (l=1) ----------------
__global__ __launch_bounds__(128) void k_plf(const half_t* __restrict__ obh,
                                             const half_t* __restrict__ pwh,
                                             const float* __restrict__ pb,
                                             const float* __restrict__ g,
                                             const float* __restrict__ bln,
                                             const half_t* __restrict__ w1h,
                                             const float* __restrict__ b1,
                                             const half_t* __restrict__ w2h,
                                             const float* __restrict__ b2,
                                             const float* __restrict__ gout,
                                             float* __restrict__ h,
                                             half_t* __restrict__ hh,
                                             float* __restrict__ out,
                                             int last) {
    int wid = blockIdx.x * 2 + (threadIdx.x >> 6);    // 0..1535
    int lane = threadIdx.x & 63;
    int lm = lane & 15, lg = lane >> 4;
    int row = wid * 16 + lm;
    const f32x4 zc = {0.f, 0.f, 0.f, 0.f};

    half4v pf[4];
#pragma unroll
    for (int kc = 0; kc < 4; ++kc)
        pf[kc] = *(const half4v*)(pwh + (size_t)lm * 64 + kc * 16 + lg * 4);

    half4v of[4];
#pragma unroll
    for (int kc = 0; kc < 4; ++kc) {
        F2H u;
        u.f2 = *(const float2*)(obh + (size_t)row * 64 + kc * 16 + lg * 4);
        of[kc] = u.h4;
    }

    f32x4 hp[4];
#pragma unroll
    for (int nt = 0; nt < 4; ++nt) {
        half4v cw[4];
#pragma unroll
        for (int kc = 0; kc < 4; ++kc) cw[kc] = pf[kc];
        if (nt < 3) {
#pragma unroll
            for (int kc = 0; kc < 4; ++kc)
                pf[kc] = *(const half4v*)(pwh + (size_t)((nt + 1) * 16 + lm) * 64 + kc * 16 + lg * 4);
        }
        f32x4 c = zc;
#pragma unroll
        for (int kc = 0; kc < 4; ++kc)
            c = __builtin_amdgcn_mfma_f32_16x16x16f16(cw[kc], of[kc], c, 0, 0, 0);
        float4 ho = *(const float4*)(h + (size_t)row * 64 + nt * 16 + lg * 4);
        float4 bb = *(const float4*)(pb + nt * 16 + lg * 4);
        hp[nt][0] = c[0] + ho.x + bb.x;
        hp[nt][1] = c[1] + ho.y + bb.y;
        hp[nt][2] = c[2] + ho.z + bb.z;
        hp[nt][3] = c[3] + ho.w + bb.w;
    }

    float s = 0.f, s2 = 0.f;
#pragma unroll
    for (int nt = 0; nt < 4; ++nt)
#pragma unroll
        for (int r = 0; r < 4; ++r) {
            s += hp[nt][r];
            s2 += hp[nt][r] * hp[nt][r];
        }
    s += __shfl_xor(s, 16);  s2 += __shfl_xor(s2, 16);
    s += __shfl_xor(s, 32);  s2 += __shfl_xor(s2, 32);
    float mean = s * (1.f / 64.f);
    float var = s2 * (1.f / 64.f) - mean * mean;
    float rstd = rsqrtf(var + 1e-5f);

    half4v xf[4];
#pragma unroll
    for (int nt = 0; nt < 4; ++nt) {
        float4 gg = *(const float4*)(g + nt * 16 + lg * 4);
        float4 bb = *(const float4*)(bln + nt * 16 + lg * 4);
        float y0 = (hp[nt][0] - mean) * rstd * gg.x + bb.x;
        float y1 = (hp[nt][1] - mean) * rstd * gg.y + bb.y;
        float y2 = (hp[nt][2] - mean) * rstd * gg.z + bb.z;
        float y3 = (hp[nt][3] - mean) * rstd * gg.w + bb.w;
        PU u;
        u.h2[0] = __builtin_amdgcn_cvt_pkrtz(y0, y1);
        u.h2[1] = __builtin_amdgcn_cvt_pkrtz(y2, y3);
        xf[nt] = u.h4;
    }

    half4v w1f[4];
#pragma unroll
    for (int kc = 0; kc < 4; ++kc)
        w1f[kc] = *(const half4v*)(w1h + (size_t)lm * 64 + kc * 16 + lg * 4);

    f32x4 acc[4] = {zc, zc, zc, zc};
#pragma unroll 4
    for (int ht = 0; ht < 16; ++ht) {
        half4v cw[4];
#pragma unroll
        for (int kc = 0; kc < 4; ++kc) cw[kc] = w1f[kc];
        half4v w2f[4];
#pragma unroll
        for (int ot = 0; ot < 4; ++ot)
            w2f[ot] = *(const half4v*)(w2h + (size_t)(ot * 16 + lm) * 256 + ht * 16 + lg * 4);
        if (ht < 15) {
#pragma unroll
            for (int kc = 0; kc < 4; ++kc)
                w1f[kc] = *(const half4v*)(w1h + (size_t)((ht + 1) * 16 + lm) * 64 + kc * 16 + lg * 4);
        }
        f32x4 c1 = zc;
#pragma unroll
        for (int kc = 0; kc < 4; ++kc)
            c1 = __builtin_amdgcn_mfma_f32_16x16x16f16(cw[kc], xf[kc], c1, 0, 0, 0);
        float4 bb = *(const float4*)(b1 + ht * 16 + lg * 4);
        float y0 = c1[0] + bb.x;
        float y1 = c1[1] + bb.y;
        float y2 = c1[2] + bb.z;
        float y3 = c1[3] + bb.w;
        y0 = 0.5f * y0 * (1.0f + erff(y0 * 0.70710678118654752f));
        y1 = 0.5f * y1 * (1.0f + erff(y1 * 0.70710678118654752f));
        y2 = 0.5f * y2 * (1.0f + erff(y2 * 0.70710678118654752f));
        y3 = 0.5f * y3 * (1.0f + erff(y3 * 0.70710678118654752f));
        PU p;
        p.h2[0] = __builtin_amdgcn_cvt_pkrtz(y0, y1);
        p.h2[1] = __builtin_amdgcn_cvt_pkrtz(y2, y3);
#pragma unroll
        for (int ot = 0; ot < 4; ++ot)
            acc[ot] = __builtin_amdgcn_mfma_f32_16x16x16f16(w2f[ot], p.h4, acc[ot], 0, 0, 0);
    }

    if (!last) {
#pragma unroll
        for (int ot = 0; ot < 4; ++ot) {
            float4 bb = *(const float4*)(b2 + ot * 16 + lg * 4);
            float4 gv = *(const float4*)(gout + (size_t)row * 64 + ot * 16 + lg * 4);
            float4 fv = make_float4(hp[ot][0] + acc[ot][0] + bb.x + gv.x,
                                    hp[ot][1] + acc[ot][1] + bb.y + gv.y,
                                    hp[ot][2] + acc[ot][2] + bb.z + gv.z,
                                    hp[ot][3] + acc[ot][3] + bb.w + gv.w);
            size_t idx = (size_t)row * 64 + ot * 16 + lg * 4;
            *(float4*)(h + idx) = fv;
            PU u;
            u.h2[0] = __builtin_amdgcn_cvt_pkrtz(fv.x, fv.y);
            u.h2[1] = __builtin_amdgcn_cvt_pkrtz(fv.z, fv.w);
            *(half4v*)(hh + idx) = u.h4;
        }
    } else {
        // direct transposed output: out[((b*64+c)*512+v)*12+t], row = (b*12+t)*512+v
        int bt = row >> 9, v = row & 511;
        int b = bt / 12, t = bt - b * 12;
        float* op = out + (size_t)b * 393216 + v * 12 + t;   // + c*6144
#pragma unroll
        for (int ot = 0; ot < 4; ++ot) {
            float4 bb = *(const float4*)(b2 + ot * 16 + lg * 4);
            float4 gv = *(const float4*)(gout + (size_t)row * 64 + ot * 16 + lg * 4);
            int c0 = ot * 16 + lg * 4;
            op[(size_t)(c0 + 0) * 6144] = hp[ot][0] + acc[ot][0] + bb.x + gv.x;
            op[(size_t)(c0 + 1) * 6144] = hp[ot][1] + acc[ot][1] + bb.y + gv.y;
            op[(size_t)(c0 + 2) * 6144] = hp[ot][2] + acc[ot][2] + bb.z + gv.z;
            op[(size_t)(c0 + 3) * 6144] = hp[ot][3] + acc[ot][3] + bb.w + gv.w;
        }
    }
}

extern "C" void kernel_launch(void* const* d_in, const int* in_sizes, int n_in,
                              void* d_out, int out_size, void* d_ws, size_t ws_size,
                              hipStream_t stream) {
    const float* x      = (const float*)d_in[0];
    const float* adj    = (const float*)d_in[1];
    const float* pos    = (const float*)d_in[2];
    const float* qkv_w  = (const float*)d_in[3];
    const float* proj_w = (const float*)d_in[4];
    const float* proj_b = (const float*)d_in[5];
    const float* ln_g   = (const float*)d_in[6];
    const float* ln_b   = (const float*)d_in[7];
    const float* ff_w1  = (const float*)d_in[8];
    const float* ff_b1  = (const float*)d_in[9];
    const float* ff_w2  = (const float*)d_in[10];
    const float* ff_b2  = (const float*)d_in[11];
    const float* gcn_w  = (const float*)d_in[12];
    const float* gcn_b  = (const float*)d_in[13];
    float* out = (float*)d_out;

    const size_t SZ = 1572864;  // 48*512*64
    float* h    = (float*)d_ws;
    float* gout = h + SZ;
    half_t* hh  = (half_t*)(gout + SZ);
    half_t* x1h = hh + SZ;
    half_t* x2h = x1h + SZ;
    half_t* qh  = x2h + SZ;
    half_t* kh  = qh + SZ;
    half_t* vh  = kh + SZ;
    half_t* obh = vh + SZ;
    half_t* adjTh  = obh + SZ;        // 262144
    half_t* adjT2h = adjTh + 262144;  // 262144
    half_t* wh     = adjT2h + 262144; // 122880
    half_t* qkv_wh  = wh;
    half_t* proj_wh = wh + 24576;
    half_t* ff_w1h  = wh + 32768;
    half_t* ff_w2h  = wh + 65536;
    half_t* gcn_wh  = wh + 98304;

    k_pre<<<632, 256, 0, stream>>>(x, pos, adj, qkv_w, proj_w, ff_w1, ff_w2, gcn_w,
                                   h, hh, adjTh, wh, adjT2h);
    for (int l = 0; l < 2; ++l) {
        k_qd<<<768, 256, 0, stream>>>(hh, qkv_wh + l * 12288, qh, kh, vh,
                                      adjTh, adjT2h, x1h, x2h);
        k_ag<<<1152, 512, 0, stream>>>(qh, kh, vh, obh, hh, x1h, x2h,
                                       gcn_wh + l * 12288, gcn_b + l * 64, gout);
        k_plf<<<768, 128, 0, stream>>>(obh, proj_wh + l * 4096, proj_b + l * 64,
                                       ln_g + l * 64, ln_b + l * 64,
                                       ff_w1h + l * 16384, ff_b1 + l * 256,
                                       ff_w2h + l * 16384, ff_b2 + l * 64, gout, h, hh,
                                       out, l);
    }
}

// Round 9
// 276.091 us; speedup vs baseline: 1.0269x; 1.0269x over previous
//
#include <hip/hip_runtime.h>
#include <math.h>

// Sizes: b=4, t=12 (BT=48), n=512, c=64, heads=8, hd=8, FF hidden=256, depth=2

typedef __fp16 half_t;
typedef __attribute__((ext_vector_type(2))) __fp16 half2v;
typedef __attribute__((ext_vector_type(4))) __fp16 half4v;
typedef __attribute__((ext_vector_type(4))) float f32x4;

union PU  { half2v h2[2]; half4v h4; };
union F4H { float4 f; half4v h[2]; };
union F2H { float2 f2; half4v h4; };

#define ATS 72
#define BTS 68
#define KLS 20
#define QLS 20
#define VTS 516

// ---------------- merged prologue: init-transpose (h+hh) | adjt | weight-prep | adj^2 ----------------
__global__ __launch_bounds__(256) void k_pre(const float* __restrict__ x,
                                             const float* __restrict__ pos,
                                             const float* __restrict__ adj,
                                             const float* __restrict__ qkv_w,
                                             const float* __restrict__ proj_w,
                                             const float* __restrict__ ff_w1,
                                             const float* __restrict__ ff_w2,
                                             const float* __restrict__ gcn_w,
                                             float* __restrict__ h,
                                             half_t* __restrict__ hh,
                                             half_t* __restrict__ adjTh,
                                             half_t* __restrict__ wh,
                                             half_t* __restrict__ adjT2h) {
    __shared__ __align__(16) char smem[17920];
    float* t = (float*)smem;                          // 64*65 floats = 16640 B
    int tid = threadIdx.x;
    int bidx = blockIdx.x;
    if (bidx < 384) {
        int b = bidx / 96, vt0 = (bidx % 96) * 64;
#pragma unroll
        for (int i = 0; i < 4; ++i) {
            int g = tid + i * 256;
            int r = g >> 4, q = g & 15;
            *(float4*)&t[r * 65 + 4 * q] =
                *(const float4*)(x + ((size_t)(b * 64 + r)) * 6144 + vt0 + 4 * q);
        }
        __syncthreads();
#pragma unroll
        for (int i = 0; i < 4; ++i) {
            int g = tid + i * 256;
            int r = g >> 4, q = g & 15;
            int vt = vt0 + r;
            int v = vt / 12, tt = vt - v * 12;
            float4 pv = *(const float4*)(pos + v * 64 + 4 * q);
            float4 o;
            o.x = t[(4 * q + 0) * 65 + r] + pv.x;
            o.y = t[(4 * q + 1) * 65 + r] + pv.y;
            o.z = t[(4 * q + 2) * 65 + r] + pv.z;
            o.w = t[(4 * q + 3) * 65 + r] + pv.w;
            size_t idx = ((size_t)((b * 12 + tt) * 512 + v)) * 64 + 4 * q;
            *(float4*)(h + idx) = o;
            PU u;
            u.h2[0] = __builtin_amdgcn_cvt_pkrtz(o.x, o.y);
            u.h2[1] = __builtin_amdgcn_cvt_pkrtz(o.z, o.w);
            *(half4v*)(hh + idx) = u.h4;
        }
    } else if (bidx < 448) {
        int fb = bidx - 384;
        int v0 = (fb & 7) * 64, w0 = (fb >> 3) * 64;
#pragma unroll
        for (int i = 0; i < 4; ++i) {
            int g = tid + i * 256;
            int r = g >> 4, q = g & 15;
            float4 a = *(const float4*)(adj + (size_t)(v0 + r) * 512 + w0 + 4 * q);
            t[(4 * q + 0) * 65 + r] = a.x;
            t[(4 * q + 1) * 65 + r] = a.y;
            t[(4 * q + 2) * 65 + r] = a.z;
            t[(4 * q + 3) * 65 + r] = a.w;
        }
        __syncthreads();
#pragma unroll
        for (int i = 0; i < 4; ++i) {
            int g = tid + i * 256;
            int rw = g >> 4, q = g & 15;
            const float* src = &t[rw * 65 + 4 * q];
            PU u;
            u.h2[0] = __builtin_amdgcn_cvt_pkrtz(src[0], src[1]);
            u.h2[1] = __builtin_amdgcn_cvt_pkrtz(src[2], src[3]);
            *(half4v*)(adjTh + (size_t)(w0 + rw) * 512 + v0 + 4 * q) = u.h4;
        }
    } else if (bidx < 928) {
        int i = (bidx - 448) * 256 + tid;
        float v;
        if (i < 24576) v = qkv_w[i];
        else if (i < 32768) v = proj_w[i - 24576];
        else if (i < 65536) v = ff_w1[i - 32768];
        else if (i < 98304) v = ff_w2[i - 65536];
        else v = gcn_w[i - 98304];
        wh[i] = (half_t)v;
    } else {
        half_t* a_t = (half_t*)smem;
        half_t* b_t = (half_t*)smem + 64 * ATS;
        int fb = bidx - 928;
        int w0 = (fb & 7) * 64, v0 = (fb >> 3) * 64;
        int wave = tid >> 6, lane = tid & 63;
        int lm = lane & 15, lg = lane >> 4;
        const f32x4 zc = {0.f, 0.f, 0.f, 0.f};
        f32x4 acc[4] = {zc, zc, zc, zc};
        for (int kc = 0; kc < 8; ++kc) {
#pragma unroll
            for (int i = 0; i < 4; ++i) {
                int g = tid + i * 256;
                int uu = g >> 4, q = g & 15;
                float4 a = *(const float4*)(adj + (size_t)(kc * 64 + uu) * 512 + w0 + 4 * q);
                a_t[(4 * q + 0) * ATS + uu] = (half_t)a.x;
                a_t[(4 * q + 1) * ATS + uu] = (half_t)a.y;
                a_t[(4 * q + 2) * ATS + uu] = (half_t)a.z;
                a_t[(4 * q + 3) * ATS + uu] = (half_t)a.w;
            }
#pragma unroll
            for (int i = 0; i < 4; ++i) {
                int g = tid + i * 256;
                int c = g >> 4, q = g & 15;
                float4 a = *(const float4*)(adj + (size_t)(v0 + c) * 512 + kc * 64 + 4 * q);
                PU u;
                u.h2[0] = __builtin_amdgcn_cvt_pkrtz(a.x, a.y);
                u.h2[1] = __builtin_amdgcn_cvt_pkrtz(a.z, a.w);
                *(half4v*)&b_t[c * BTS + 4 * q] = u.h4;
            }
            __syncthreads();
#pragma unroll
            for (int k16 = 0; k16 < 4; ++k16) {
                half4v af = *(const half4v*)&a_t[(wave * 16 + lm) * ATS + k16 * 16 + lg * 4];
#pragma unroll
                for (int nt = 0; nt < 4; ++nt) {
                    half4v bf = *(const half4v*)&b_t[(nt * 16 + lm) * BTS + k16 * 16 + lg * 4];
                    acc[nt] = __builtin_amdgcn_mfma_f32_16x16x16f16(af, bf, acc[nt], 0, 0, 0);
                }
            }
            __syncthreads();
        }
#pragma unroll
        for (int nt = 0; nt < 4; ++nt)
#pragma unroll
            for (int r = 0; r < 4; ++r)
                adjT2h[(size_t)(w0 + wave * 16 + lg * 4 + r) * 512 + v0 + nt * 16 + lm] =
                    (half_t)acc[nt][r];
    }
}

// ---------------- merged: qkv (blocks 0..383) | diff z-merged (blocks 384..767) ----------------
__global__ __launch_bounds__(256) void k_qd(const half_t* __restrict__ hh,
                                            const half_t* __restrict__ Wh,
                                            half_t* __restrict__ qh,
                                            half_t* __restrict__ kh,
                                            half_t* __restrict__ vh,
                                            const half_t* __restrict__ adjTh,
                                            const half_t* __restrict__ adjT2h,
                                            half_t* __restrict__ x1h,
                                            half_t* __restrict__ x2h) {
    __shared__ __align__(16) half_t sbuf[2 * 64 * ATS + 64 * BTS];   // 27136 B
    int tid = threadIdx.x;
    int bidx = blockIdx.x;
    int wave = tid >> 6, lane = tid & 63;
    int lm = lane & 15, lg = lane >> 4;
    const f32x4 zc = {0.f, 0.f, 0.f, 0.f};

    if (bidx < 384) {
        int wid = bidx * 4 + wave;
        int row = wid * 16 + lm;
        half4v xf[4];
#pragma unroll
        for (int kc = 0; kc < 4; ++kc) {
            F2H u;
            u.f2 = *(const float2*)(hh + (size_t)row * 64 + kc * 16 + lg * 4);
            xf[kc] = u.h4;
        }
        const float SC = 0.35355339059327373f * 1.4426950408889634f;
        int bt = row >> 9, v = row & 511;
        half4v wf[4];
#pragma unroll
        for (int kc = 0; kc < 4; ++kc)
            wf[kc] = *(const half4v*)(Wh + (size_t)lm * 64 + kc * 16 + lg * 4);
#pragma unroll
        for (int nt = 0; nt < 12; ++nt) {
            half4v cw[4];
#pragma unroll
            for (int kc = 0; kc < 4; ++kc) cw[kc] = wf[kc];
            if (nt < 11) {
#pragma unroll
                for (int kc = 0; kc < 4; ++kc)
                    wf[kc] = *(const half4v*)(Wh + (size_t)((nt + 1) * 16 + lm) * 64 + kc * 16 + lg * 4);
            }
            f32x4 acc = zc;
#pragma unroll
            for (int kc = 0; kc < 4; ++kc)
                acc = __builtin_amdgcn_mfma_f32_16x16x16f16(cw[kc], xf[kc], acc, 0, 0, 0);
            int s = nt >> 2;
            if (s == 0) { acc[0] *= SC; acc[1] *= SC; acc[2] *= SC; acc[3] *= SC; }
            int head = ((nt & 3) << 1) + (lg >> 1);
            int d0 = (lg & 1) * 4;
            PU o2;
            o2.h2[0] = __builtin_amdgcn_cvt_pkrtz(acc[0], acc[1]);
            o2.h2[1] = __builtin_amdgcn_cvt_pkrtz(acc[2], acc[3]);
            half_t* dst = (s == 0) ? qh : ((s == 1) ? kh : vh);
            *(half4v*)(dst + ((size_t)(bt * 8 + head) * 512 + v) * 8 + d0) = o2.h4;
        }
    } else {
        half_t* a_t  = sbuf;
        half_t* a2_t = sbuf + 64 * ATS;
        half_t* b_t  = sbuf + 2 * 64 * ATS;
        int fb = bidx - 384;                    // 0..383
        int w0 = (fb & 7) * 64;
        int bt = fb >> 3;
        f32x4 acc0[4] = {zc, zc, zc, zc};
        f32x4 acc1[4] = {zc, zc, zc, zc};
        for (int kc = 0; kc < 8; ++kc) {
#pragma unroll
            for (int i = 0; i < 4; ++i) {       // 1024 items: 512 adjTh + 512 adjT2h
                int g = tid + i * 256;
                if (g < 512) {
                    int r = g >> 3, s = g & 7;
                    *(float4*)&a_t[r * ATS + s * 8] =
                        *(const float4*)(adjTh + (size_t)(w0 + r) * 512 + kc * 64 + s * 8);
                } else {
                    int g2 = g - 512;
                    int r = g2 >> 3, s = g2 & 7;
                    *(float4*)&a2_t[r * ATS + s * 8] =
                        *(const float4*)(adjT2h + (size_t)(w0 + r) * 512 + kc * 64 + s * 8);
                }
            }
#pragma unroll
            for (int i = 0; i < 2; ++i) {       // 512 items: transpose-stage hh tile
                int g = tid + i * 256;
                int vr = g >> 3, s = g & 7;
                F4H u;
                u.f = *(const float4*)(hh + ((size_t)(bt * 512 + kc * 64 + vr)) * 64 + s * 8);
#pragma unroll
                for (int e = 0; e < 8; ++e)
                    b_t[(s * 8 + e) * BTS + vr] = u.h[e >> 2][e & 3];
            }
            __syncthreads();
#pragma unroll
            for (int k16 = 0; k16 < 4; ++k16) {
                half4v af0 = *(const half4v*)&a_t[(wave * 16 + lm) * ATS + k16 * 16 + lg * 4];
                half4v af1 = *(const half4v*)&a2_t[(wave * 16 + lm) * ATS + k16 * 16 + lg * 4];
#pragma unroll
                for (int nt = 0; nt < 4; ++nt) {
                    half4v bf = *(const half4v*)&b_t[(nt * 16 + lm) * BTS + k16 * 16 + lg * 4];
                    acc0[nt] = __builtin_amdgcn_mfma_f32_16x16x16f16(af0, bf, acc0[nt], 0, 0, 0);
                    acc1[nt] = __builtin_amdgcn_mfma_f32_16x16x16f16(af1, bf, acc1[nt], 0, 0, 0);
                }
            }
            __syncthreads();
        }
#pragma unroll
        for (int nt = 0; nt < 4; ++nt)
#pragma unroll
            for (int r = 0; r < 4; ++r) {
                size_t o = (size_t)(w0 + wave * 16 + lg * 4 + r) * 3072 + bt * 64 + nt * 16 + lm;
                x1h[o] = (half_t)acc0[nt][r];
                x2h[o] = (half_t)acc1[nt][r];
            }
    }
}

// ---------------- merged: attn (blocks 0..767) | gcn (blocks 768..1151) ----------------
__global__ __launch_bounds__(512) void k_ag(const half_t* __restrict__ qh,
                                            const half_t* __restrict__ kh,
                                            const half_t* __restrict__ vh,
                                            half_t* __restrict__ obh,
                                            const half_t* __restrict__ hh,
                                            const half_t* __restrict__ x1h,
                                            const half_t* __restrict__ x2h,
                                            const half_t* __restrict__ Wh,
                                            const float* __restrict__ bias,
                                            float* __restrict__ gout) {
    __shared__ __align__(16) half_t sbuf[512 * KLS + 16 * VTS + 256 * QLS];  // 47232 B
    int tid = threadIdx.x;
    int bidx = blockIdx.x;
    const half4v zero4 = {(__fp16)0.f, (__fp16)0.f, (__fp16)0.f, (__fp16)0.f};
    const f32x4 zc = {0.f, 0.f, 0.f, 0.f};

    if (bidx < 768) {
        half_t* kl = sbuf;
        half_t* vt = sbuf + 512 * KLS;
        half_t* ql = sbuf + 512 * KLS + 16 * VTS;
        int bh = bidx >> 1;
        int half_ = bidx & 1;
        const half_t* kbase = kh + (size_t)bh * 4096;
        const half_t* vbase = vh + (size_t)bh * 4096;
        const half_t* qbase = qh + (size_t)bh * 4096 + half_ * 2048;

        if (tid < 256) {
#pragma unroll
            for (int kk = 0; kk < 2; ++kk) {
                int key = tid * 2 + kk;
                F4H u;
                u.f = *(const float4*)(kbase + key * 8);
                half4v* rowp = (half4v*)&kl[key * KLS];
                rowp[0] = u.h[0];
                rowp[1] = u.h[1];
                rowp[2] = zero4;
                rowp[3] = zero4;
            }
            {
                F4H u;
                u.f = *(const float4*)(qbase + tid * 8);
                half4v* rowp = (half4v*)&ql[tid * QLS];
                rowp[0] = u.h[0];
                rowp[1] = u.h[1];
                rowp[2] = zero4;
                rowp[3] = zero4;
            }
            {
                int k0 = tid * 2;
                F4H a, b;
                a.f = *(const float4*)(vbase + k0 * 8);
                b.f = *(const float4*)(vbase + k0 * 8 + 8);
#pragma unroll
                for (int d = 0; d < 8; ++d) {
                    half2v p = {a.h[d >> 2][d & 3], b.h[d >> 2][d & 3]};
                    *(half2v*)&vt[d * VTS + k0] = p;
                }
            }
        }
        for (int i = tid; i < 1032; i += 512)
            ((half4v*)(vt + 8 * VTS))[i] = zero4;
        __syncthreads();

        int wave = tid >> 6, lane = tid & 63;
        int lm = lane & 15, lg = lane >> 4;
        int bt = bh >> 3, head = bh & 7;

#pragma unroll 1
        for (int st = 0; st < 2; ++st) {
            int qrow0 = wave * 32 + st * 16;
            half4v qf = *(const half4v*)&ql[(qrow0 + lm) * QLS + lg * 4];
            f32x4 acc = zc;
            float l0 = 0.f, l1 = 0.f, l2 = 0.f, l3 = 0.f;
#pragma unroll 4
            for (int kt = 0; kt < 32; ++kt) {
                int key0 = kt * 16;
                half4v ka = *(const half4v*)&kl[(key0 + lm) * KLS + lg * 4];
                f32x4 c1 = __builtin_amdgcn_mfma_f32_16x16x16f16(ka, qf, zc, 0, 0, 0);
                float p0 = exp2f(fminf(c1[0], 12.f));
                float p1 = exp2f(fminf(c1[1], 12.f));
                float p2 = exp2f(fminf(c1[2], 12.f));
                float p3 = exp2f(fminf(c1[3], 12.f));
                l0 += p0; l1 += p1; l2 += p2; l3 += p3;
                PU pu;
                pu.h2[0] = __builtin_amdgcn_cvt_pkrtz(p0, p1);
                pu.h2[1] = __builtin_amdgcn_cvt_pkrtz(p2, p3);
                half4v va = *(const half4v*)&vt[lm * VTS + key0 + lg * 4];
                acc = __builtin_amdgcn_mfma_f32_16x16x16f16(va, pu.h4, acc, 0, 0, 0);
            }
            float lsum = (l0 + l1) + (l2 + l3);
            lsum += __shfl_xor(lsum, 16);
            lsum += __shfl_xor(lsum, 32);
            if (lg < 2) {
                float inv = 1.f / lsum;
                int rowg = half_ * 256 + qrow0 + lm;
                PU o2;
                o2.h2[0] = __builtin_amdgcn_cvt_pkrtz(acc[0] * inv, acc[1] * inv);
                o2.h2[1] = __builtin_amdgcn_cvt_pkrtz(acc[2] * inv, acc[3] * inv);
                *(half4v*)(obh + ((size_t)(bt * 512 + rowg)) * 64 + head * 8 + lg * 4) = o2.h4;
            }
        }
    } else {
        half_t* a_t = sbuf;
        half_t* b_t = sbuf + 64 * ATS;
        int row0 = (bidx - 768) * 64;
        int wave = tid >> 6, lane = tid & 63;
        int lm = lane & 15, lg = lane >> 4;
        f32x4 acc[4] = {zc, zc, zc, zc};

        for (int ch = 0; ch < 3; ++ch) {
            if (tid < 256) {
                if (ch == 0) {
#pragma unroll
                    for (int i = 0; i < 2; ++i) {
                        int g = tid + i * 256;
                        int r = g >> 3, s = g & 7;
                        int rowg = row0 + r;
                        int v = rowg / 48, bt = rowg - v * 48;
                        *(float4*)&a_t[r * ATS + s * 8] =
                            *(const float4*)(hh + ((size_t)(bt * 512 + v)) * 64 + s * 8);
                    }
                } else {
                    const half_t* X = (ch == 1) ? x1h : x2h;
#pragma unroll
                    for (int i = 0; i < 2; ++i) {
                        int g = tid + i * 256;
                        int r = g >> 3, s = g & 7;
                        *(float4*)&a_t[r * ATS + s * 8] =
                            *(const float4*)(X + (size_t)(row0 + r) * 64 + s * 8);
                    }
                }
#pragma unroll
                for (int i = 0; i < 4; ++i) {
                    int g = tid + i * 256;
                    int r = g >> 4, q = g & 15;
                    *(half4v*)&b_t[r * BTS + 4 * q] =
                        *(const half4v*)(Wh + (size_t)r * 192 + ch * 64 + 4 * q);
                }
            }
            __syncthreads();
            if (tid < 256) {
#pragma unroll
                for (int k16 = 0; k16 < 4; ++k16) {
                    half4v af = *(const half4v*)&a_t[(wave * 16 + lm) * ATS + k16 * 16 + lg * 4];
#pragma unroll
                    for (int nt = 0; nt < 4; ++nt) {
                        half4v bf = *(const half4v*)&b_t[(nt * 16 + lm) * BTS + k16 * 16 + lg * 4];
                        acc[nt] = __builtin_amdgcn_mfma_f32_16x16x16f16(bf, af, acc[nt], 0, 0, 0);
                    }
                }
            }
            __syncthreads();
        }
        if (tid < 256) {
            int row = row0 + wave * 16 + lm;
            int v = row / 48, bt = row - v * 48;
            float* gp = gout + ((size_t)(bt * 512 + v)) * 64;
#pragma unroll
            for (int nt = 0; nt < 4; ++nt) {
                float4 bb = *(const float4*)(bias + nt * 16 + lg * 4);
                *(float4*)(gp + nt * 16 + lg * 4) =
                    make_float4(acc[nt][0] + bb.x, acc[nt][1] + bb.y,
                                acc[nt][2] + bb.z, acc[nt][3] + bb.w);
            }
        }
    }
}

// ---------------- fused proj + LN + FF + gout add; writes h/hh (l=0) or out (l=1) ----------------
__global__ __launch_bounds__(128) void k_plf(const half_t* __restrict__ obh,
                                             const half_t* __restrict__ pwh,
                                             const float* __restrict__ pb,
                                             const float* __restrict__ g,
                                             const float* __restrict__ bln,
                                             const half_t* __restrict__ w1h,
                                             const float* __restrict__ b1,
                                             const half_t* __restrict__ w2h,
                                             const float* __restrict__ b2,
                                             const float* __restrict__ gout,
                                             float* __restrict__ h,
                                             half_t* __restrict__ hh,
                                             float* __restrict__ out,
                                             int last) {
    int wid = blockIdx.x * 2 + (threadIdx.x >> 6);    // 0..1535
    int lane = threadIdx.x & 63;
    int lm = lane & 15, lg = lane >> 4;
    int row = wid * 16 + lm;
    const f32x4 zc = {0.f, 0.f, 0.f, 0.f};

    half4v pf[4];
#pragma unroll
    for (int kc = 0; kc < 4; ++kc)
        pf[kc] = *(const half4v*)(pwh + (size_t)lm * 64 + kc * 16 + lg * 4);

    half4v of[4];
#pragma unroll
    for (int kc = 0; kc < 4; ++kc) {
        F2H u;
        u.f2 = *(const float2*)(obh + (size_t)row * 64 + kc * 16 + lg * 4);
        of[kc] = u.h4;
    }

    f32x4 hp[4];
#pragma unroll
    for (int nt = 0; nt < 4; ++nt) {
        half4v cw[4];
#pragma unroll
        for (int kc = 0; kc < 4; ++kc) cw[kc] = pf[kc];
        if (nt < 3) {
#pragma unroll
            for (int kc = 0; kc < 4; ++kc)
                pf[kc] = *(const half4v*)(pwh + (size_t)((nt + 1) * 16 + lm) * 64 + kc * 16 + lg * 4);
        }
        f32x4 c = zc;
#pragma unroll
        for (int kc = 0; kc < 4; ++kc)
            c = __builtin_amdgcn_mfma_f32_16x16x16f16(cw[kc], of[kc], c, 0, 0, 0);
        float4 ho = *(const float4*)(h + (size_t)row * 64 + nt * 16 + lg * 4);
        float4 bb = *(const float4*)(pb + nt * 16 + lg * 4);
        hp[nt][0] = c[0] + ho.x + bb.x;
        hp[nt][1] = c[1] + ho.y + bb.y;
        hp[nt][2] = c[2] + ho.z + bb.z;
        hp[nt][3] = c[3] + ho.w + bb.w;
    }

    float s = 0.f, s2 = 0.f;
#pragma unroll
    for (int nt = 0; nt < 4; ++nt)
#pragma unroll
        for (int r = 0; r < 4; ++r) {
            s += hp[nt][r];
            s2 += hp[nt][r] * hp[nt][r];
        }
    s += __shfl_xor(s, 16);  s2 += __shfl_xor(s2, 16);
    s += __shfl_xor(s, 32);  s2 += __shfl_xor(s2, 32);
    float mean = s * (1.f / 64.f);
    float var = s2 * (1.f / 64.f) - mean * mean;
    float rstd = rsqrtf(var + 1e-5f);

    half4v xf[4];
#pragma unroll
    for (int nt = 0; nt < 4; ++nt) {
        float4 gg = *(const float4*)(g + nt * 16 + lg * 4);
        float4 bb = *(const float4*)(bln + nt * 16 + lg * 4);
        float y0 = (hp[nt][0] - mean) * rstd * gg.x + bb.x;
        float y1 = (hp[nt][1] - mean) * rstd * gg.y + bb.y;
        float y2 = (hp[nt][2] - mean) * rstd * gg.z + bb.z;
        float y3 = (hp[nt][3] - mean) * rstd * gg.w + bb.w;
        PU u;
        u.h2[0] = __builtin_amdgcn_cvt_pkrtz(y0, y1);
        u.h2[1] = __builtin_amdgcn_cvt_pkrtz(y2, y3);
        xf[nt] = u.h4;
    }

    half4v w1f[4];
#pragma unroll
    for (int kc = 0; kc < 4; ++kc)
        w1f[kc] = *(const half4v*)(w1h + (size_t)lm * 64 + kc * 16 + lg * 4);

    f32x4 acc[4] = {zc, zc, zc, zc};
#pragma unroll 4
    for (int ht = 0; ht < 16; ++ht) {
        half4v cw[4];
#pragma unroll
        for (int kc = 0; kc < 4; ++kc) cw[kc] = w1f[kc];
        half4v w2f[4];
#pragma unroll
        for (int ot = 0; ot < 4; ++ot)
            w2f[ot] = *(const half4v*)(w2h + (size_t)(ot * 16 + lm) * 256 + ht * 16 + lg * 4);
        if (ht < 15) {
#pragma unroll
            for (int kc = 0; kc < 4; ++kc)
                w1f[kc] = *(const half4v*)(w1h + (size_t)((ht + 1) * 16 + lm) * 64 + kc * 16 + lg * 4);
        }
        f32x4 c1 = zc;
#pragma unroll
        for (int kc = 0; kc < 4; ++kc)
            c1 = __builtin_amdgcn_mfma_f32_16x16x16f16(cw[kc], xf[kc], c1, 0, 0, 0);
        float4 bb = *(const float4*)(b1 + ht * 16 + lg * 4);
        float y0 = c1[0] + bb.x;
        float y1 = c1[1] + bb.y;
        float y2 = c1[2] + bb.z;
        float y3 = c1[3] + bb.w;
        y0 = 0.5f * y0 * (1.0f + erff(y0 * 0.70710678118654752f));
        y1 = 0.5f * y1 * (1.0f + erff(y1 * 0.70710678118654752f));
        y2 = 0.5f * y2 * (1.0f + erff(y2 * 0.70710678118654752f));
        y3 = 0.5f * y3 * (1.0f + erff(y3 * 0.70710678118654752f));
        PU p;
        p.h2[0] = __builtin_amdgcn_cvt_pkrtz(y0, y1);
        p.h2[1] = __builtin_amdgcn_cvt_pkrtz(y2, y3);
#pragma unroll
        for (int ot = 0; ot < 4; ++ot)
            acc[ot] = __builtin_amdgcn_mfma_f32_16x16x16f16(w2f[ot], p.h4, acc[ot], 0, 0, 0);
    }

    if (!last) {
#pragma unroll
        for (int ot = 0; ot < 4; ++ot) {
            float4 bb = *(const float4*)(b2 + ot * 16 + lg * 4);
            float4 gv = *(const float4*)(gout + (size_t)row * 64 + ot * 16 + lg * 4);
            float4 fv = make_float4(hp[ot][0] + acc[ot][0] + bb.x + gv.x,
                                    hp[ot][1] + acc[ot][1] + bb.y + gv.y,
                                    hp[ot][2] + acc[ot][2] + bb.z + gv.z,
                                    hp[ot][3] + acc[ot][3] + bb.w + gv.w);
            size_t idx = (size_t)row * 64 + ot * 16 + lg * 4;
            *(float4*)(h + idx) = fv;
            PU u;
            u.h2[0] = __builtin_amdgcn_cvt_pkrtz(fv.x, fv.y);
            u.h2[1] = __builtin_amdgcn_cvt_pkrtz(fv.z, fv.w);
            *(half4v*)(hh + idx) = u.h4;
        }
    } else {
        // direct transposed output: out[((b*64+c)*512+v)*12+t], row = (b*12+t)*512+v
        int bt = row >> 9, v = row & 511;
        int b = bt / 12, t = bt - b * 12;
        float* op = out + (size_t)b * 393216 + v * 12 + t;   // + c*6144
#pragma unroll
        for (int ot = 0; ot < 4; ++ot) {
            float4 bb = *(const float4*)(b2 + ot * 16 + lg * 4);
            float4 gv = *(const float4*)(gout + (size_t)row * 64 + ot * 16 + lg * 4);
            int c0 = ot * 16 + lg * 4;
            op[(size_t)(c0 + 0) * 6144] = hp[ot][0] + acc[ot][0] + bb.x + gv.x;
            op[(size_t)(c0 + 1) * 6144] = hp[ot][1] + acc[ot][1] + bb.y + gv.y;
            op[(size_t)(c0 + 2) * 6144] = hp[ot][2] + acc[ot][2] + bb.z + gv.z;
            op[(size_t)(c0 + 3) * 6144] = hp[ot][3] + acc[ot][3] + bb.w + gv.w;
        }
    }
}

extern "C" void kernel_launch(void* const* d_in, const int* in_sizes, int n_in,
                              void* d_out, int out_size, void* d_ws, size_t ws_size,
                              hipStream_t stream) {
    const float* x      = (const float*)d_in[0];
    const float* adj    = (const float*)d_in[1];
    const float* pos    = (const float*)d_in[2];
    const float* qkv_w  = (const float*)d_in[3];
    const float* proj_w = (const float*)d_in[4];
    const float* proj_b = (const float*)d_in[5];
    const float* ln_g   = (const float*)d_in[6];
    const float* ln_b   = (const float*)d_in[7];
    const float* ff_w1  = (const float*)d_in[8];
    const float* ff_b1  = (const float*)d_in[9];
    const float* ff_w2  = (const float*)d_in[10];
    const float* ff_b2  = (const float*)d_in[11];
    const float* gcn_w  = (const float*)d_in[12];
    const float* gcn_b  = (const float*)d_in[13];
    float* out = (float*)d_out;

    const size_t SZ = 1572864;  // 48*512*64
    float* h    = (float*)d_ws;
    float* gout = h + SZ;
    half_t* hh  = (half_t*)(gout + SZ);
    half_t* x1h = hh + SZ;
    half_t* x2h = x1h + SZ;
    half_t* qh  = x2h + SZ;
    half_t* kh  = qh + SZ;
    half_t* vh  = kh + SZ;
    half_t* obh = vh + SZ;
    half_t* adjTh  = obh + SZ;        // 262144
    half_t* adjT2h = adjTh + 262144;  // 262144
    half_t* wh     = adjT2h + 262144; // 122880
    half_t* qkv_wh  = wh;
    half_t* proj_wh = wh + 24576;
    half_t* ff_w1h  = wh + 32768;
    half_t* ff_w2h  = wh + 65536;
    half_t* gcn_wh  = wh + 98304;

    k_pre<<<992, 256, 0, stream>>>(x, pos, adj, qkv_w, proj_w, ff_w1, ff_w2, gcn_w,
                                   h, hh, adjTh, wh, adjT2h);
    for (int l = 0; l < 2; ++l) {
        k_qd<<<768, 256, 0, stream>>>(hh, qkv_wh + l * 12288, qh, kh, vh,
                                      adjTh, adjT2h, x1h, x2h);
        k_ag<<<1152, 512, 0, stream>>>(qh, kh, vh, obh, hh, x1h, x2h,
                                       gcn_wh + l * 12288, gcn_b + l * 64, gout);
        k_plf<<<768, 128, 0, stream>>>(obh, proj_wh + l * 4096, proj_b + l * 64,
                                       ln_g + l * 64, ln_b + l * 64,
                                       ff_w1h + l * 16384, ff_b1 + l * 256,
                                       ff_w2h + l * 16384, ff_b2 + l * 64, gout, h, hh,
                                       out, l);
    }
}